// Round 1
// baseline (876.662 us; speedup 1.0000x reference)
//
#include <hip/hip_runtime.h>
#include <hip/hip_bf16.h>
#include <hip/hip_fp16.h>

#define B_ 4
#define T_ 1024
#define E_ 256
#define V_ 32000
#define NAX 12
#define NCOMP 24
#define NSTATE 576
#define MTOK 4096

using f16x8 = __attribute__((ext_vector_type(8))) _Float16;
using f32x4 = __attribute__((ext_vector_type(4))) float;

__device__ __forceinline__ void g2l16(const void* g, void* l) {
    __builtin_amdgcn_global_load_lds((const __attribute__((address_space(1))) void*)g,
                                     (__attribute__((address_space(3))) void*)l, 16, 0, 0);
}

// ---------------- Kernel 1: embed -> a -> c (one wave per token) ----------------
__global__ __launch_bounds__(256) void tok_kernel(
    const int* __restrict__ ids, const float* __restrict__ emb,
    const float* __restrict__ W_ax, const float* __restrict__ b_ax,
    const float* __restrict__ g_ax, const float* __restrict__ beta_ax,
    const float* __restrict__ W_comp, const float* __restrict__ b_comp,
    const float* __restrict__ g_comp, const float* __restrict__ beta_comp,
    float* __restrict__ c_out)
{
    const int lane = threadIdx.x & 63;
    const int wid  = threadIdx.x >> 6;
    const int tok  = blockIdx.x * 4 + wid;
    const int id   = ids[tok];
    const float4 x4 = *reinterpret_cast<const float4*>(emb + (size_t)id * E_ + lane * 4);

    float a[NAX];
#pragma unroll
    for (int j = 0; j < NAX; ++j) {
        const float4 w4 = *reinterpret_cast<const float4*>(W_ax + j * E_ + lane * 4);
        float p = w4.x * x4.x + w4.y * x4.y + w4.z * x4.z + w4.w * x4.w;
#pragma unroll
        for (int off = 32; off; off >>= 1) p += __shfl_xor(p, off);
        a[j] = p + b_ax[j];
    }
    // LayerNorm over 12 (redundant on all lanes)
    float mu = 0.f;
#pragma unroll
    for (int j = 0; j < NAX; ++j) mu += a[j];
    mu *= (1.f / NAX);
    float var = 0.f;
#pragma unroll
    for (int j = 0; j < NAX; ++j) { float d = a[j] - mu; var += d * d; }
    var *= (1.f / NAX);
    const float rs = rsqrtf(var + 1e-5f);
#pragma unroll
    for (int j = 0; j < NAX; ++j) a[j] = tanhf((a[j] - mu) * rs * g_ax[j] + beta_ax[j]);

    // c_pre: lane < 24 owns one output channel
    float cp = 0.f;
    if (lane < NCOMP) {
        cp = b_comp[lane];
#pragma unroll
        for (int j = 0; j < NAX; ++j) cp += W_comp[lane * NAX + j] * a[j];
    }
    // LN across lanes 0..23 (lanes >=24 contribute 0)
    float s1 = cp;
#pragma unroll
    for (int off = 32; off; off >>= 1) s1 += __shfl_xor(s1, off);
    const float mu2 = s1 * (1.f / NCOMP);
    const float dd = cp - mu2;
    float s2 = (lane < NCOMP) ? dd * dd : 0.f;
#pragma unroll
    for (int off = 32; off; off >>= 1) s2 += __shfl_xor(s2, off);
    const float rs2 = rsqrtf(s2 * (1.f / NCOMP) + 1e-5f);
    if (lane < NCOMP) {
        const float cv = tanhf(dd * rs2 * g_comp[lane] + beta_comp[lane]);
        c_out[(size_t)tok * NCOMP + lane] = cv;
    }
}

// ---------------- Kernel 2: sequential scan over T, emit flat (f16) + final (f32) ----------------
__global__ __launch_bounds__(576) void scan_kernel(
    const float* __restrict__ c, const float* __restrict__ decay_p,
    const float* __restrict__ mix_p, _Float16* __restrict__ flat,
    float* __restrict__ final_out)
{
    const int b = blockIdx.x;
    const int s = threadIdx.x;           // 0..575
    const int i = s / NCOMP, j = s - i * NCOMP;
    const float d = 1.f / (1.f + expf(-decay_p[0]));
    const float m = 1.f / (1.f + expf(-mix_p[0]));
    const float* cb = c + (size_t)b * T_ * NCOMP;
    _Float16* fb = flat + (size_t)b * T_ * NSTATE;
    float st = 0.f;
    for (int t = 0; t < T_; ++t) {
        const float ci = cb[t * NCOMP + i];
        const float cj = cb[t * NCOMP + j];
        st = d * st + m * ci * cj;
        fb[(size_t)t * NSTATE + s] = (_Float16)st;
    }
    final_out[b * NSTATE + s] = st;
}

// ---------------- f32 -> f16 cast (vectorized, 8/thread) ----------------
__global__ __launch_bounds__(256) void cast_kernel(const float* __restrict__ src,
                                                   _Float16* __restrict__ dst, int n)
{
    const int i = (blockIdx.x * 256 + threadIdx.x) * 8;
    if (i >= n) return;
    const float4 a = *reinterpret_cast<const float4*>(src + i);
    const float4 b = *reinterpret_cast<const float4*>(src + i + 4);
    f16x8 v;
    v[0] = (_Float16)a.x; v[1] = (_Float16)a.y; v[2] = (_Float16)a.z; v[3] = (_Float16)a.w;
    v[4] = (_Float16)b.x; v[5] = (_Float16)b.y; v[6] = (_Float16)b.z; v[7] = (_Float16)b.w;
    *reinterpret_cast<f16x8*>(dst + i) = v;
}

// ---------------- MFMA GEMM: C[M,N] = A[M,K] * Bm[N,K]^T + bias ----------------
// 128x128 tile, BK=32, 4 waves (2x2), each wave 64x64 via 4x4 frags of 16x16x32.
// EPI==0: write f32 (logits). EPI==1: exact-erf GELU, write f16 (h).
template<int EPI>
__global__ __launch_bounds__(256) void gemm_kernel(
    const _Float16* __restrict__ A, const _Float16* __restrict__ Bm,
    const float* __restrict__ bias, float* __restrict__ outF,
    _Float16* __restrict__ outH, int M, int N, int K)
{
    __shared__ _Float16 As[128 * 32];
    __shared__ _Float16 Bs[128 * 32];
    const int tid  = threadIdx.x;
    const int lane = tid & 63;
    const int wid  = tid >> 6;
    const int wm = (wid >> 1) * 64, wn = (wid & 1) * 64;
    const int fr = lane & 15, kg = lane >> 4;
    const int tM = blockIdx.y * 128, tN = blockIdx.x * 128;

    // staging: 512 chunks of 16B per tile; thread t takes chunks t and t+256
    const int rowL = tid >> 2;
    const int kcH  = (tid & 3) * 8;
    const _Float16* gA0 = A + (size_t)(tM + rowL) * K + kcH;
    const _Float16* gA1 = gA0 + (size_t)64 * K;
    const _Float16* gB0 = Bm + (size_t)(tN + rowL) * K + kcH;
    const _Float16* gB1 = gB0 + (size_t)64 * K;
    _Float16* lA0 = As + tid * 8;
    _Float16* lA1 = As + (tid + 256) * 8;
    _Float16* lB0 = Bs + tid * 8;
    _Float16* lB1 = Bs + (tid + 256) * 8;

    f32x4 acc[4][4] = {};

    for (int kt = 0; kt < K; kt += 32) {
        __syncthreads();
        g2l16(gA0 + kt, lA0);
        g2l16(gA1 + kt, lA1);
        g2l16(gB0 + kt, lB0);
        g2l16(gB1 + kt, lB1);
        __syncthreads();
        f16x8 af[4], bf[4];
#pragma unroll
        for (int m = 0; m < 4; ++m)
            af[m] = *reinterpret_cast<const f16x8*>(As + (wm + m * 16 + fr) * 32 + kg * 8);
#pragma unroll
        for (int n = 0; n < 4; ++n)
            bf[n] = *reinterpret_cast<const f16x8*>(Bs + (wn + n * 16 + fr) * 32 + kg * 8);
#pragma unroll
        for (int m = 0; m < 4; ++m)
#pragma unroll
            for (int n = 0; n < 4; ++n)
                acc[m][n] = __builtin_amdgcn_mfma_f32_16x16x32_f16(af[m], bf[n], acc[m][n], 0, 0, 0);
    }

#pragma unroll
    for (int m = 0; m < 4; ++m) {
        const int rg = tM + wm + m * 16 + kg * 4;
#pragma unroll
        for (int n = 0; n < 4; ++n) {
            const int cg = tN + wn + n * 16 + fr;
            const float bv = bias[cg];
#pragma unroll
            for (int r = 0; r < 4; ++r) {
                float v = acc[m][n][r] + bv;
                if (EPI == 1) {
                    v = 0.5f * v * (1.f + erff(v * 0.70710678118654752f));
                    outH[(size_t)(rg + r) * N + cg] = (_Float16)v;
                } else {
                    outF[(size_t)(rg + r) * N + cg] = v;
                }
            }
        }
    }
}

extern "C" void kernel_launch(void* const* d_in, const int* in_sizes, int n_in,
                              void* d_out, int out_size, void* d_ws, size_t ws_size,
                              hipStream_t stream)
{
    const int*   ids     = (const int*)  d_in[0];
    const float* emb     = (const float*)d_in[1];
    const float* W_ax    = (const float*)d_in[2];
    const float* b_ax    = (const float*)d_in[3];
    const float* g_ax    = (const float*)d_in[4];
    const float* beta_ax = (const float*)d_in[5];
    const float* W_comp  = (const float*)d_in[6];
    const float* b_comp  = (const float*)d_in[7];
    const float* g_comp  = (const float*)d_in[8];
    const float* beta_cp = (const float*)d_in[9];
    const float* decay_p = (const float*)d_in[10];
    const float* mix_p   = (const float*)d_in[11];
    const float* W1      = (const float*)d_in[12];
    const float* b1      = (const float*)d_in[13];
    const float* W2      = (const float*)d_in[14];
    const float* b2      = (const float*)d_in[15];
    float* out = (float*)d_out;

    // workspace layout (256B-aligned blocks)
    char* w = (char*)d_ws;
    float*    c_ws   = (float*)(w);                 // 4096*24*4     = 393216 B
    _Float16* flat16 = (_Float16*)(w + 393216);     // 4096*576*2    = 4718592 B
    _Float16* h16    = (_Float16*)(w + 5111808);    // 4096*512*2    = 4194304 B
    _Float16* W1h    = (_Float16*)(w + 9306112);    // 512*576*2     = 589824 B
    _Float16* W2h    = (_Float16*)(w + 9895936);    // 32000*512*2   = 32768000 B  (total ~42.7 MB)

    cast_kernel<<<144, 256, 0, stream>>>(W1, W1h, 512 * 576);
    cast_kernel<<<8000, 256, 0, stream>>>(W2, W2h, V_ * 512);
    tok_kernel<<<1024, 256, 0, stream>>>(ids, emb, W_ax, b_ax, g_ax, beta_ax,
                                         W_comp, b_comp, g_comp, beta_cp, c_ws);
    scan_kernel<<<4, 576, 0, stream>>>(c_ws, decay_p, mix_p, flat16,
                                       out + (size_t)MTOK * V_);
    gemm_kernel<1><<<dim3(512 / 128, MTOK / 128), 256, 0, stream>>>(
        flat16, W1h, b1, nullptr, h16, MTOK, 512, 576);
    gemm_kernel<0><<<dim3(V_ / 128, MTOK / 128), 256, 0, stream>>>(
        h16, W2h, b2, out, nullptr, MTOK, V_, 512);
}